// Round 15
// baseline (230.561 us; speedup 1.0000x reference)
//
#include <hip/hip_runtime.h>

typedef __bf16 bf16_t;
typedef __attribute__((ext_vector_type(8))) __bf16 bf16x8;
typedef __attribute__((ext_vector_type(4))) float f32x4;
typedef unsigned int uint;
typedef unsigned short ushort;
typedef unsigned char uchar;

#define N_NODES 50000
#define C_IN 16
#define NT 4
#define K1 4
#define KEIG 128
#define E_EDGES 1600000
#define HID 512
#define OUT_F 256
#define FEAT 64           // NT*C
#define CONVF 256         // K1*FEAT
#define M_PAD 50048       // ceil(N/128)*128
#define CPB 1024          // coeff_partial blocks
#define RED1 64           // stage-1 output blocks (CPB/16)
// staged radix CSR build
#define SH_C 8            // coarse bucket = dst >> 8 (256 nodes per bucket)
#define NBC 196           // ceil(N/256)
#define CAPC 8704         // per-coarse-bucket record capacity (mean 8163 + 6 sigma)
#define PA_B 782          // pass A blocks (782*2048 >= E)

__device__ inline uint bfbits(float f) {
    bf16_t b = (bf16_t)f;
    return (uint)__builtin_bit_cast(unsigned short, b);
}
__device__ inline float bfu(uint u) {
    return __uint_as_float(u << 16);
}

// ---------------------------------------------------------------- coeff (+ evecs->bf16 fused)
__global__ void coeff_partial_kernel(const float* __restrict__ evecs,
                                     const float* __restrict__ x,
                                     float* __restrict__ partial,
                                     bf16_t* __restrict__ evb, int n) {
    __shared__ float lds[4 * 2048];
    int t = threadIdx.x, lane = t & 63, wid = t >> 6;
    int gw = blockIdx.x * 4 + wid;
    int total_w = gridDim.x * 4;
    int rpw = (n + total_w - 1) / total_w;
    int r0 = gw * rpw;
    int r1 = min(n, r0 + rpw);
    float acc0[16], acc1[16];
#pragma unroll
    for (int c = 0; c < 16; c++) { acc0[c] = 0.f; acc1[c] = 0.f; }
    for (int r = r0; r < r1; r++) {
        float e0 = evecs[(size_t)r * KEIG + lane];
        float e1 = evecs[(size_t)r * KEIG + 64 + lane];
        evb[(size_t)r * KEIG + lane] = (bf16_t)e0;
        evb[(size_t)r * KEIG + 64 + lane] = (bf16_t)e1;
        const float* xr = &x[(size_t)r * C_IN];
#pragma unroll
        for (int c = 0; c < 16; c++) {
            float xv = xr[c];
            acc0[c] += e0 * xv;
            acc1[c] += e1 * xv;
        }
    }
#pragma unroll
    for (int c = 0; c < 16; c++) {
        lds[wid * 2048 + c * 128 + lane] = acc0[c];
        lds[wid * 2048 + c * 128 + 64 + lane] = acc1[c];
    }
    __syncthreads();
    for (int idx = t; idx < 2048; idx += 256) {
        float s = lds[idx] + lds[2048 + idx] + lds[4096 + idx] + lds[6144 + idx];
        partial[(size_t)blockIdx.x * 2048 + idx] = s;
    }
}

__global__ void coeff_reduce1_kernel(const float* __restrict__ partial,
                                     float* __restrict__ partial2) {
    int g = blockIdx.x >> 3;
    int idx = (blockIdx.x & 7) * 256 + threadIdx.x;
    float s = 0.f;
#pragma unroll
    for (int j = 0; j < 16; j++)
        s += partial[(size_t)(g * 16 + j) * 2048 + idx];
    partial2[(size_t)g * 2048 + idx] = s;
}

__global__ void coeff_reduce2_kernel(const float* __restrict__ partial2,
                                     float* __restrict__ coeff) {
    int idx = blockIdx.x * 256 + threadIdx.x;
    float s = 0.f;
#pragma unroll 8
    for (int b = 0; b < RED1; b++) s += partial2[(size_t)b * 2048 + idx];
    coeff[idx] = s;
}

__global__ void sc2t_kernel(const float* __restrict__ evals,
                            const float* __restrict__ taus,
                            const float* __restrict__ coeff,
                            bf16_t* __restrict__ sc2t) {
    int idx = blockIdx.x * 256 + threadIdx.x;   // < 8192
    int col = idx >> 7, k = idx & 127;
    float v = expf(-evals[k] * taus[col >> 4]) * coeff[(col & 15) * 128 + k];
    sc2t[col * KEIG + k] = (bf16_t)v;
}

// diffb[M_PAD x 64] = evb[M_PAD x 128] @ sc2t[64 x 128]^T via MFMA
#define DSTR 136
__global__ void diffusion_mfma_kernel(const bf16_t* __restrict__ evb,
                                      const bf16_t* __restrict__ sc2t,
                                      bf16_t* __restrict__ diffb) {
    __shared__ bf16_t Alds[128 * DSTR];
    __shared__ bf16_t Blds[64 * DSTR];
    const int t = threadIdx.x;
    const int lane = t & 63;
    const int wid = t >> 6;
    const int row0 = blockIdx.x * 128;
#pragma unroll
    for (int i = 0; i < 8; i++) {
        int idx = t + i * 256;
        int r = idx >> 4;
        int k8 = (idx & 15) * 8;
        *(uint4*)&Alds[r * DSTR + k8] =
            *(const uint4*)&evb[(size_t)(row0 + r) * KEIG + k8];
    }
#pragma unroll
    for (int i = 0; i < 4; i++) {
        int idx = t + i * 256;
        int r = idx >> 4;
        int k8 = (idx & 15) * 8;
        *(uint4*)&Blds[r * DSTR + k8] =
            *(const uint4*)&sc2t[r * KEIG + k8];
    }
    __syncthreads();
    f32x4 acc[2][4];
#pragma unroll
    for (int m = 0; m < 2; m++)
#pragma unroll
        for (int n = 0; n < 4; n++) acc[m][n] = (f32x4){0.f, 0.f, 0.f, 0.f};
#pragma unroll
    for (int kk = 0; kk < 128; kk += 32) {
        int ko = kk + ((lane >> 4) << 3);
        bf16x8 av[2], bv[4];
#pragma unroll
        for (int m = 0; m < 2; m++)
            av[m] = *(const bf16x8*)&Alds[(wid * 32 + m * 16 + (lane & 15)) * DSTR + ko];
#pragma unroll
        for (int n = 0; n < 4; n++)
            bv[n] = *(const bf16x8*)&Blds[(n * 16 + (lane & 15)) * DSTR + ko];
#pragma unroll
        for (int m = 0; m < 2; m++)
#pragma unroll
            for (int n = 0; n < 4; n++)
                acc[m][n] = __builtin_amdgcn_mfma_f32_16x16x32_bf16(
                    av[m], bv[n], acc[m][n], 0, 0, 0);
    }
#pragma unroll
    for (int m = 0; m < 2; m++) {
#pragma unroll
        for (int n = 0; n < 4; n++) {
            int col = n * 16 + (lane & 15);
#pragma unroll
            for (int q = 0; q < 4; q++) {
                int row = row0 + wid * 32 + m * 16 + ((lane >> 4) << 2) + q;
                diffb[(size_t)row * FEAT + col] = (bf16_t)acc[m][n][q];
            }
        }
    }
}

// ---------------------------------------------------------------- CSR build: staged radix
// Record: [src | k0,k1 bf16 | k2,k3 bf16 | dst&255]
__global__ void radixA_kernel(const int* __restrict__ src,
                              const int* __restrict__ dst,
                              const float* __restrict__ kvals,
                              int* __restrict__ gcursor,     // NBC, stride 16 ints
                              int4* __restrict__ bucket, int E) {
    __shared__ int hist[256];
    __shared__ int lds_off[256];
    __shared__ int cnt2[256];
    __shared__ int run_base[256];
    __shared__ int4 recs[2048];
    __shared__ uchar posb[2048];
    int t = threadIdx.x;
    hist[t] = 0; cnt2[t] = 0;
    __syncthreads();
    int e0 = blockIdx.x * 2048;
    int total = min(2048, E - e0);
    int d[8];
#pragma unroll
    for (int j = 0; j < 8; j++) {
        int e = e0 + j * 256 + t;
        d[j] = (e < E) ? dst[e] : -1;
        if (d[j] >= 0) atomicAdd(&hist[d[j] >> SH_C], 1);
    }
    __syncthreads();
    int own = hist[t];
    lds_off[t] = own;
    __syncthreads();
    for (int o = 1; o < 256; o <<= 1) {
        int v = (t >= o) ? lds_off[t - o] : 0;
        __syncthreads();
        lds_off[t] += v;
        __syncthreads();
    }
    int excl = lds_off[t] - own;
    __syncthreads();
    lds_off[t] = excl;
    __syncthreads();
#pragma unroll
    for (int j = 0; j < 8; j++) {
        if (d[j] < 0) continue;
        int e = e0 + j * 256 + t;
        int b = d[j] >> SH_C;
        int r = atomicAdd(&cnt2[b], 1);
        int pos = lds_off[b] + r;
        uint w01 = bfbits(kvals[e]) | (bfbits(kvals[(size_t)E + e]) << 16);
        uint w23 = bfbits(kvals[2 * (size_t)E + e]) | (bfbits(kvals[3 * (size_t)E + e]) << 16);
        int4 rec;
        rec.x = src[e]; rec.y = (int)w01; rec.z = (int)w23; rec.w = d[j] & 255;
        recs[pos] = rec;
        posb[pos] = (uchar)b;
    }
    if (t < NBC) {
        int c = hist[t];
        run_base[t] = c ? atomicAdd(&gcursor[t * 16], c) : 0;
    }
    __syncthreads();
    for (int i = t; i < total; i += 256) {
        int b = posb[i];
        int g = run_base[b] + (i - lds_off[b]);
        if (g < CAPC) bucket[(size_t)b * CAPC + g] = recs[i];
    }
}

__global__ void coarse_scan_kernel(const int* __restrict__ gcursor,
                                   int* __restrict__ coarse_base,
                                   int* __restrict__ row_start) {
    __shared__ int lds[256];
    int t = threadIdx.x;
    int own = (t < NBC) ? min(gcursor[t * 16], CAPC) : 0;
    lds[t] = own;
    __syncthreads();
    for (int o = 1; o < 256; o <<= 1) {
        int v = (t >= o) ? lds[t - o] : 0;
        __syncthreads();
        lds[t] += v;
        __syncthreads();
    }
    if (t < NBC) coarse_base[t] = lds[t] - own;
    if (t == 255) row_start[N_NODES] = lds[255];
}

__global__ void radixB_kernel(const int4* __restrict__ bucket,
                              const int* __restrict__ gcursor,
                              const int* __restrict__ coarse_base,
                              int4* __restrict__ csr_rec,
                              int* __restrict__ row_start) {
    __shared__ int hist[256];
    __shared__ int off[256];
    __shared__ int cnt2[256];
    int b = blockIdx.x, t = threadIdx.x;
    int n = min(gcursor[b * 16], CAPC);
    int base = coarse_base[b];
    hist[t] = 0; cnt2[t] = 0;
    __syncthreads();
    const int4* brec = &bucket[(size_t)b * CAPC];
    for (int i = t; i < n; i += 256) atomicAdd(&hist[brec[i].w & 255], 1);
    __syncthreads();
    int own = hist[t];
    off[t] = own;
    __syncthreads();
    for (int o = 1; o < 256; o <<= 1) {
        int v = (t >= o) ? off[t - o] : 0;
        __syncthreads();
        off[t] += v;
        __syncthreads();
    }
    int excl = off[t] - own;
    __syncthreads();
    off[t] = excl;
    __syncthreads();
    int g = b * 256 + t;
    if (g < N_NODES) row_start[g] = base + off[t];
    for (int i = t; i < n; i += 256) {
        int4 rec = brec[i];
        int w = rec.w & 255;
        int r = atomicAdd(&cnt2[w], 1);
        csr_rec[(size_t)(base + off[w] + r)] = rec;
    }
}

// ---------------------------------------------------------------- aniso conv
// wave per node, lane = channel. 8-deep batches with record prefetch:
// batch k+1's (wave-uniform, scalar-pipe) record loads are issued while
// batch k's 8 gathers are in flight — overlaps the two chain legs.
__global__ void aniso_kernel(const bf16_t* __restrict__ diffb_,
                             const int* __restrict__ row_start,
                             const int4* __restrict__ csr_rec,
                             bf16_t* __restrict__ conv, int n) {
    const ushort* diffb = (const ushort*)diffb_;
    int wid = (blockIdx.x * 256 + threadIdx.x) >> 6;
    int lane = threadIdx.x & 63;
    if (wid >= n) return;
    int start = __builtin_amdgcn_readfirstlane(row_start[wid]);
    int end = __builtin_amdgcn_readfirstlane(row_start[wid + 1]);
    float a0 = 0.f, a1 = 0.f, a2 = 0.f, a3 = 0.f;
    int p = start;
    if (p + 8 <= end) {
        int s[8];
        uint wy[8], wz[8];
#pragma unroll
        for (int j = 0; j < 8; j++) {
            int4 rec = csr_rec[p + j];
            s[j] = rec.x; wy[j] = (uint)rec.y; wz[j] = (uint)rec.z;
        }
        while (true) {
            // issue gathers for current batch
            float h[8];
#pragma unroll
            for (int j = 0; j < 8; j++)
                h[j] = bfu((uint)diffb[(size_t)s[j] * FEAT + lane]);
            int pn = p + 8;
            bool more = (pn + 8 <= end);
            int sn[8];
            uint wyn[8], wzn[8];
            if (more) {
                // prefetch next batch's records (scalar pipe) under the gathers
#pragma unroll
                for (int j = 0; j < 8; j++) {
                    int4 rec = csr_rec[pn + j];
                    sn[j] = rec.x; wyn[j] = (uint)rec.y; wzn[j] = (uint)rec.z;
                }
            }
#pragma unroll
            for (int j = 0; j < 8; j++) {
                a0 += __uint_as_float(wy[j] << 16) * h[j];
                a1 += __uint_as_float(wy[j] & 0xffff0000u) * h[j];
                a2 += __uint_as_float(wz[j] << 16) * h[j];
                a3 += __uint_as_float(wz[j] & 0xffff0000u) * h[j];
            }
            p = pn;
            if (!more) break;
#pragma unroll
            for (int j = 0; j < 8; j++) {
                s[j] = sn[j]; wy[j] = wyn[j]; wz[j] = wzn[j];
            }
        }
    }
    for (; p < end; p++) {
        int4 rec = csr_rec[p];
        float h0 = bfu((uint)diffb[(size_t)rec.x * FEAT + lane]);
        uint y = (uint)rec.y, z = (uint)rec.z;
        a0 += __uint_as_float(y << 16) * h0;
        a1 += __uint_as_float(y & 0xffff0000u) * h0;
        a2 += __uint_as_float(z << 16) * h0;
        a3 += __uint_as_float(z & 0xffff0000u) * h0;
    }
    size_t base = (size_t)wid * CONVF + lane;
    conv[base]       = (bf16_t)a0;
    conv[base + 64]  = (bf16_t)a1;
    conv[base + 128] = (bf16_t)a2;
    conv[base + 192] = (bf16_t)a3;
}

// ---------------------------------------------------------------- weights
__global__ void convw_kernel(const float* __restrict__ W, bf16_t* __restrict__ Wt,
                             int rows, int cols) {
    int idx = blockIdx.x * 256 + threadIdx.x;
    if (idx >= rows * cols) return;
    int o = idx / rows, f = idx % rows;
    Wt[idx] = (bf16_t)W[(size_t)f * cols + o];
}

// ---------------------------------------------------------------- GEMM
#define BM 128
#define BN 128
#define BK 64
#define LSTR 72   // LDS row stride in elements (144 B: 16B-aligned, breaks bank-conflict stride)

template <int EPI>
__global__ void gemm_bf16_kernel(const bf16_t* __restrict__ A,
                                 const bf16_t* __restrict__ Bt,
                                 const float* __restrict__ bias,
                                 void* __restrict__ Cout,
                                 int Nn, int K, int Mvalid) {
    __shared__ bf16_t Alds[BM * LSTR];
    __shared__ bf16_t Blds[BN * LSTR];
    const int t = threadIdx.x;
    const int lane = t & 63;
    const int wid = t >> 6;
    const int row0 = blockIdx.y * BM;
    const int col0 = blockIdx.x * BN;
    const int wr = (wid >> 1) * 64;
    const int wc = (wid & 1) * 64;

    f32x4 acc[4][4];
#pragma unroll
    for (int m = 0; m < 4; m++)
#pragma unroll
        for (int n = 0; n < 4; n++) acc[m][n] = (f32x4){0.f, 0.f, 0.f, 0.f};

    for (int kt = 0; kt < K; kt += BK) {
#pragma unroll
        for (int i = 0; i < 4; i++) {
            int idx = t + i * 256;
            int r = idx >> 3;
            int k8 = (idx & 7) * 8;
            *(uint4*)&Alds[r * LSTR + k8] =
                *(const uint4*)&A[(size_t)(row0 + r) * K + kt + k8];
            *(uint4*)&Blds[r * LSTR + k8] =
                *(const uint4*)&Bt[(size_t)(col0 + r) * K + kt + k8];
        }
        __syncthreads();
#pragma unroll
        for (int kk = 0; kk < BK; kk += 32) {
            int ko = kk + ((lane >> 4) << 3);
            bf16x8 av[4], bv[4];
#pragma unroll
            for (int m = 0; m < 4; m++)
                av[m] = *(const bf16x8*)&Alds[(wr + m * 16 + (lane & 15)) * LSTR + ko];
#pragma unroll
            for (int n = 0; n < 4; n++)
                bv[n] = *(const bf16x8*)&Blds[(wc + n * 16 + (lane & 15)) * LSTR + ko];
#pragma unroll
            for (int m = 0; m < 4; m++)
#pragma unroll
                for (int n = 0; n < 4; n++)
                    acc[m][n] = __builtin_amdgcn_mfma_f32_16x16x32_bf16(
                        av[m], bv[n], acc[m][n], 0, 0, 0);
        }
        __syncthreads();
    }

#pragma unroll
    for (int n = 0; n < 4; n++) {
        int col = col0 + wc + n * 16 + (lane & 15);
        float bvl = bias[col];
#pragma unroll
        for (int m = 0; m < 4; m++) {
#pragma unroll
            for (int r = 0; r < 4; r++) {
                int row = row0 + wr + m * 16 + ((lane >> 4) << 2) + r;
                float v = acc[m][n][r] + bvl;
                if (EPI == 0) {
                    v = v > 0.f ? v : 0.f;
                    ((bf16_t*)Cout)[(size_t)row * Nn + col] = (bf16_t)v;
                } else {
                    if (row < Mvalid)
                        ((float*)Cout)[(size_t)row * Nn + col] = v;
                }
            }
        }
    }
}

// ---------------------------------------------------------------- normalize
__global__ void norm_kernel(float* __restrict__ out, int n) {
    int w = (blockIdx.x * 256 + threadIdx.x) >> 6;
    int lane = threadIdx.x & 63;
    if (w >= n) return;
    float4 v = *(float4*)&out[(size_t)w * OUT_F + lane * 4];
    float ss = v.x * v.x + v.y * v.y + v.z * v.z + v.w * v.w;
#pragma unroll
    for (int off = 32; off > 0; off >>= 1) ss += __shfl_xor(ss, off);
    float nrm = sqrtf(ss);
    nrm = nrm > 1e-12f ? nrm : 1e-12f;
    float sc = 1.f / nrm;
    v.x *= sc; v.y *= sc; v.z *= sc; v.w *= sc;
    *(float4*)&out[(size_t)w * OUT_F + lane * 4] = v;
}

// ---------------------------------------------------------------- launch
extern "C" void kernel_launch(void* const* d_in, const int* in_sizes, int n_in,
                              void* d_out, int out_size, void* d_ws, size_t ws_size,
                              hipStream_t stream) {
    const float* x      = (const float*)d_in[0];
    const float* evals  = (const float*)d_in[1];
    const float* evecs  = (const float*)d_in[2];
    const float* taus   = (const float*)d_in[3];
    const float* kvals  = (const float*)d_in[4];
    const int*   eidx   = (const int*)d_in[5];
    const float* W1     = (const float*)d_in[6];
    const float* b1     = (const float*)d_in[7];
    const float* W2     = (const float*)d_in[8];
    const float* b2     = (const float*)d_in[9];
    float* out = (float*)d_out;

    const int N = N_NODES, E = E_EDGES;
    const int* e_src = eidx;
    const int* e_dst = eidx + E;

    // workspace layout (bytes, 256-aligned)
    char* ws = (char*)d_ws;
    size_t off = 0;
    auto alloc = [&](size_t bytes) {
        void* p = ws + off;
        off = (off + bytes + 255) & ~(size_t)255;
        return p;
    };
    float* coeff       = (float*)alloc(2048 * 4);
    float* partial     = (float*)alloc((size_t)CPB * 2048 * 4);
    float* partial2    = (float*)alloc((size_t)RED1 * 2048 * 4);
    bf16_t* evb        = (bf16_t*)alloc((size_t)M_PAD * KEIG * 2);
    bf16_t* sc2t       = (bf16_t*)alloc((size_t)FEAT * KEIG * 2);
    bf16_t* diffb      = (bf16_t*)alloc((size_t)M_PAD * FEAT * 2);
    int*   gcursor     = (int*)alloc((size_t)NBC * 16 * 4);
    int*   coarse_base = (int*)alloc((size_t)(NBC + 1) * 4);
    int*   row_start   = (int*)alloc((size_t)(N + 1) * 4);
    // csr_rec (16B/edge, dead after aniso) aliases h1 (bf16 M_PAD x HID)
    size_t csr_bytes = (size_t)E * 16;
    size_t h1_bytes  = (size_t)M_PAD * HID * 2;
    int4*  csr_rec   = (int4*)alloc(csr_bytes > h1_bytes ? csr_bytes : h1_bytes);
    bf16_t* h1       = (bf16_t*)csr_rec;
    // bucket region (dead after radixB) aliases conv (written by aniso)
    size_t bucket_bytes = (size_t)NBC * CAPC * 16;
    size_t conv_bytes   = (size_t)M_PAD * CONVF * 2;
    int4*  bucket    = (int4*)alloc(bucket_bytes > conv_bytes ? bucket_bytes : conv_bytes);
    bf16_t* conv     = (bf16_t*)bucket;
    bf16_t* w1t      = (bf16_t*)alloc((size_t)HID * CONVF * 2);
    bf16_t* w2t      = (bf16_t*)alloc((size_t)OUT_F * HID * 2);
    (void)ws_size;

    hipMemsetAsync(gcursor, 0, (size_t)NBC * 16 * 4, stream);

    // diffusion: coeff (+evb conversion), 2-stage reduce, sc2t, MFMA GEMM
    coeff_partial_kernel<<<CPB, 256, 0, stream>>>(evecs, x, partial, evb, N);
    coeff_reduce1_kernel<<<RED1 * 8, 256, 0, stream>>>(partial, partial2);
    coeff_reduce2_kernel<<<8, 256, 0, stream>>>(partial2, coeff);
    sc2t_kernel<<<32, 256, 0, stream>>>(evals, taus, coeff, sc2t);
    diffusion_mfma_kernel<<<M_PAD / 128, 256, 0, stream>>>(evb, sc2t, diffb);

    // CSR build: staged radix (A: LDS-sorted coalesced bins; B: L2-local sort)
    radixA_kernel<<<PA_B, 256, 0, stream>>>(e_src, e_dst, kvals, gcursor, bucket, E);
    coarse_scan_kernel<<<1, 256, 0, stream>>>(gcursor, coarse_base, row_start);
    radixB_kernel<<<NBC, 256, 0, stream>>>(bucket, gcursor, coarse_base,
                                           csr_rec, row_start);

    // aniso conv -> bf16 [M_PAD x 256] (overwrites bucket region; CSR still live)
    aniso_kernel<<<(N + 3) / 4, 256, 0, stream>>>(diffb, row_start, csr_rec, conv, N);

    // weights -> transposed bf16
    convw_kernel<<<(CONVF * HID + 255) / 256, 256, 0, stream>>>(W1, w1t, CONVF, HID);
    convw_kernel<<<(HID * OUT_F + 255) / 256, 256, 0, stream>>>(W2, w2t, HID, OUT_F);

    // MLP (h1 overwrites csr_rec region — CSR dead after aniso)
    dim3 g1(HID / BN, M_PAD / BM);
    gemm_bf16_kernel<0><<<g1, 256, 0, stream>>>(conv, w1t, b1, h1, HID, CONVF, N);
    dim3 g2(OUT_F / BN, M_PAD / BM);
    gemm_bf16_kernel<1><<<g2, 256, 0, stream>>>(h1, w2t, b2, out, OUT_F, HID, N);

    // L2 normalize in place
    norm_kernel<<<(N + 3) / 4, 256, 0, stream>>>(out, N);
}

// Round 16
// 221.796 us; speedup vs baseline: 1.0395x; 1.0395x over previous
//
#include <hip/hip_runtime.h>

typedef __bf16 bf16_t;
typedef __attribute__((ext_vector_type(8))) __bf16 bf16x8;
typedef __attribute__((ext_vector_type(4))) float f32x4;
typedef unsigned int uint;
typedef unsigned short ushort;
typedef unsigned char uchar;

#define N_NODES 50000
#define C_IN 16
#define NT 4
#define K1 4
#define KEIG 128
#define E_EDGES 1600000
#define HID 512
#define OUT_F 256
#define FEAT 64           // NT*C
#define CONVF 256         // K1*FEAT
#define M_PAD 50048       // ceil(N/128)*128
#define CPB 1024          // coeff_partial blocks
#define RED1 64           // stage-1 output blocks (CPB/16)
// staged radix CSR build
#define SH_C 8            // coarse bucket = dst >> 8 (256 nodes per bucket)
#define NBC 196           // ceil(N/256)
#define CAPC 8704         // per-coarse-bucket record capacity (mean 8163 + 6 sigma)
#define PA_B 782          // pass A blocks (782*2048 >= E)

__device__ inline uint bfbits(float f) {
    bf16_t b = (bf16_t)f;
    return (uint)__builtin_bit_cast(unsigned short, b);
}
__device__ inline float bfu(uint u) {
    return __uint_as_float(u << 16);
}
// async global->LDS, 16B per lane. lds dest must be wave-uniform base + lane*16.
__device__ inline void gload16(const bf16_t* g, bf16_t* l) {
    __builtin_amdgcn_global_load_lds((const __attribute__((address_space(1))) void*)g,
                                     (__attribute__((address_space(3))) void*)l,
                                     16, 0, 0);
}

// ---------------------------------------------------------------- coeff (+ evecs->bf16 fused)
__global__ void coeff_partial_kernel(const float* __restrict__ evecs,
                                     const float* __restrict__ x,
                                     float* __restrict__ partial,
                                     bf16_t* __restrict__ evb, int n) {
    __shared__ float lds[4 * 2048];
    int t = threadIdx.x, lane = t & 63, wid = t >> 6;
    int gw = blockIdx.x * 4 + wid;
    int total_w = gridDim.x * 4;
    int rpw = (n + total_w - 1) / total_w;
    int r0 = gw * rpw;
    int r1 = min(n, r0 + rpw);
    float acc0[16], acc1[16];
#pragma unroll
    for (int c = 0; c < 16; c++) { acc0[c] = 0.f; acc1[c] = 0.f; }
    for (int r = r0; r < r1; r++) {
        float e0 = evecs[(size_t)r * KEIG + lane];
        float e1 = evecs[(size_t)r * KEIG + 64 + lane];
        evb[(size_t)r * KEIG + lane] = (bf16_t)e0;
        evb[(size_t)r * KEIG + 64 + lane] = (bf16_t)e1;
        const float* xr = &x[(size_t)r * C_IN];
#pragma unroll
        for (int c = 0; c < 16; c++) {
            float xv = xr[c];
            acc0[c] += e0 * xv;
            acc1[c] += e1 * xv;
        }
    }
#pragma unroll
    for (int c = 0; c < 16; c++) {
        lds[wid * 2048 + c * 128 + lane] = acc0[c];
        lds[wid * 2048 + c * 128 + 64 + lane] = acc1[c];
    }
    __syncthreads();
    for (int idx = t; idx < 2048; idx += 256) {
        float s = lds[idx] + lds[2048 + idx] + lds[4096 + idx] + lds[6144 + idx];
        partial[(size_t)blockIdx.x * 2048 + idx] = s;
    }
}

__global__ void coeff_reduce1_kernel(const float* __restrict__ partial,
                                     float* __restrict__ partial2) {
    int g = blockIdx.x >> 3;
    int idx = (blockIdx.x & 7) * 256 + threadIdx.x;
    float s = 0.f;
#pragma unroll
    for (int j = 0; j < 16; j++)
        s += partial[(size_t)(g * 16 + j) * 2048 + idx];
    partial2[(size_t)g * 2048 + idx] = s;
}

__global__ void coeff_reduce2_kernel(const float* __restrict__ partial2,
                                     float* __restrict__ coeff) {
    int idx = blockIdx.x * 256 + threadIdx.x;
    float s = 0.f;
#pragma unroll 8
    for (int b = 0; b < RED1; b++) s += partial2[(size_t)b * 2048 + idx];
    coeff[idx] = s;
}

__global__ void sc2t_kernel(const float* __restrict__ evals,
                            const float* __restrict__ taus,
                            const float* __restrict__ coeff,
                            bf16_t* __restrict__ sc2t) {
    int idx = blockIdx.x * 256 + threadIdx.x;   // < 8192
    int col = idx >> 7, k = idx & 127;
    float v = expf(-evals[k] * taus[col >> 4]) * coeff[(col & 15) * 128 + k];
    sc2t[col * KEIG + k] = (bf16_t)v;
}

// diffb[M_PAD x 64] = evb[M_PAD x 128] @ sc2t[64 x 128]^T via MFMA
#define DSTR 136
__global__ void diffusion_mfma_kernel(const bf16_t* __restrict__ evb,
                                      const bf16_t* __restrict__ sc2t,
                                      bf16_t* __restrict__ diffb) {
    __shared__ bf16_t Alds[128 * DSTR];
    __shared__ bf16_t Blds[64 * DSTR];
    const int t = threadIdx.x;
    const int lane = t & 63;
    const int wid = t >> 6;
    const int row0 = blockIdx.x * 128;
#pragma unroll
    for (int i = 0; i < 8; i++) {
        int idx = t + i * 256;
        int r = idx >> 4;
        int k8 = (idx & 15) * 8;
        *(uint4*)&Alds[r * DSTR + k8] =
            *(const uint4*)&evb[(size_t)(row0 + r) * KEIG + k8];
    }
#pragma unroll
    for (int i = 0; i < 4; i++) {
        int idx = t + i * 256;
        int r = idx >> 4;
        int k8 = (idx & 15) * 8;
        *(uint4*)&Blds[r * DSTR + k8] =
            *(const uint4*)&sc2t[r * KEIG + k8];
    }
    __syncthreads();
    f32x4 acc[2][4];
#pragma unroll
    for (int m = 0; m < 2; m++)
#pragma unroll
        for (int n = 0; n < 4; n++) acc[m][n] = (f32x4){0.f, 0.f, 0.f, 0.f};
#pragma unroll
    for (int kk = 0; kk < 128; kk += 32) {
        int ko = kk + ((lane >> 4) << 3);
        bf16x8 av[2], bv[4];
#pragma unroll
        for (int m = 0; m < 2; m++)
            av[m] = *(const bf16x8*)&Alds[(wid * 32 + m * 16 + (lane & 15)) * DSTR + ko];
#pragma unroll
        for (int n = 0; n < 4; n++)
            bv[n] = *(const bf16x8*)&Blds[(n * 16 + (lane & 15)) * DSTR + ko];
#pragma unroll
        for (int m = 0; m < 2; m++)
#pragma unroll
            for (int n = 0; n < 4; n++)
                acc[m][n] = __builtin_amdgcn_mfma_f32_16x16x32_bf16(
                    av[m], bv[n], acc[m][n], 0, 0, 0);
    }
#pragma unroll
    for (int m = 0; m < 2; m++) {
#pragma unroll
        for (int n = 0; n < 4; n++) {
            int col = n * 16 + (lane & 15);
#pragma unroll
            for (int q = 0; q < 4; q++) {
                int row = row0 + wid * 32 + m * 16 + ((lane >> 4) << 2) + q;
                diffb[(size_t)row * FEAT + col] = (bf16_t)acc[m][n][q];
            }
        }
    }
}

// ---------------------------------------------------------------- CSR build: staged radix
// Record: [src | k0,k1 bf16 | k2,k3 bf16 | dst&255]
__global__ void radixA_kernel(const int* __restrict__ src,
                              const int* __restrict__ dst,
                              const float* __restrict__ kvals,
                              int* __restrict__ gcursor,     // NBC, stride 16 ints
                              int4* __restrict__ bucket, int E) {
    __shared__ int hist[256];
    __shared__ int lds_off[256];
    __shared__ int cnt2[256];
    __shared__ int run_base[256];
    __shared__ int4 recs[2048];
    __shared__ uchar posb[2048];
    int t = threadIdx.x;
    hist[t] = 0; cnt2[t] = 0;
    __syncthreads();
    int e0 = blockIdx.x * 2048;
    int total = min(2048, E - e0);
    int d[8];
#pragma unroll
    for (int j = 0; j < 8; j++) {
        int e = e0 + j * 256 + t;
        d[j] = (e < E) ? dst[e] : -1;
        if (d[j] >= 0) atomicAdd(&hist[d[j] >> SH_C], 1);
    }
    __syncthreads();
    int own = hist[t];
    lds_off[t] = own;
    __syncthreads();
    for (int o = 1; o < 256; o <<= 1) {
        int v = (t >= o) ? lds_off[t - o] : 0;
        __syncthreads();
        lds_off[t] += v;
        __syncthreads();
    }
    int excl = lds_off[t] - own;
    __syncthreads();
    lds_off[t] = excl;
    __syncthreads();
#pragma unroll
    for (int j = 0; j < 8; j++) {
        if (d[j] < 0) continue;
        int e = e0 + j * 256 + t;
        int b = d[j] >> SH_C;
        int r = atomicAdd(&cnt2[b], 1);
        int pos = lds_off[b] + r;
        uint w01 = bfbits(kvals[e]) | (bfbits(kvals[(size_t)E + e]) << 16);
        uint w23 = bfbits(kvals[2 * (size_t)E + e]) | (bfbits(kvals[3 * (size_t)E + e]) << 16);
        int4 rec;
        rec.x = src[e]; rec.y = (int)w01; rec.z = (int)w23; rec.w = d[j] & 255;
        recs[pos] = rec;
        posb[pos] = (uchar)b;
    }
    if (t < NBC) {
        int c = hist[t];
        run_base[t] = c ? atomicAdd(&gcursor[t * 16], c) : 0;
    }
    __syncthreads();
    for (int i = t; i < total; i += 256) {
        int b = posb[i];
        int g = run_base[b] + (i - lds_off[b]);
        if (g < CAPC) bucket[(size_t)b * CAPC + g] = recs[i];
    }
}

__global__ void coarse_scan_kernel(const int* __restrict__ gcursor,
                                   int* __restrict__ coarse_base,
                                   int* __restrict__ row_start) {
    __shared__ int lds[256];
    int t = threadIdx.x;
    int own = (t < NBC) ? min(gcursor[t * 16], CAPC) : 0;
    lds[t] = own;
    __syncthreads();
    for (int o = 1; o < 256; o <<= 1) {
        int v = (t >= o) ? lds[t - o] : 0;
        __syncthreads();
        lds[t] += v;
        __syncthreads();
    }
    if (t < NBC) coarse_base[t] = lds[t] - own;
    if (t == 255) row_start[N_NODES] = lds[255];
}

__global__ void radixB_kernel(const int4* __restrict__ bucket,
                              const int* __restrict__ gcursor,
                              const int* __restrict__ coarse_base,
                              int4* __restrict__ csr_rec,
                              int* __restrict__ row_start) {
    __shared__ int hist[256];
    __shared__ int off[256];
    __shared__ int cnt2[256];
    int b = blockIdx.x, t = threadIdx.x;
    int n = min(gcursor[b * 16], CAPC);
    int base = coarse_base[b];
    hist[t] = 0; cnt2[t] = 0;
    __syncthreads();
    const int4* brec = &bucket[(size_t)b * CAPC];
    for (int i = t; i < n; i += 256) atomicAdd(&hist[brec[i].w & 255], 1);
    __syncthreads();
    int own = hist[t];
    off[t] = own;
    __syncthreads();
    for (int o = 1; o < 256; o <<= 1) {
        int v = (t >= o) ? off[t - o] : 0;
        __syncthreads();
        off[t] += v;
        __syncthreads();
    }
    int excl = off[t] - own;
    __syncthreads();
    off[t] = excl;
    __syncthreads();
    int g = b * 256 + t;
    if (g < N_NODES) row_start[g] = base + off[t];
    for (int i = t; i < n; i += 256) {
        int4 rec = brec[i];
        int w = rec.w & 255;
        int r = atomicAdd(&cnt2[w], 1);
        csr_rec[(size_t)(base + off[w] + r)] = rec;
    }
}

// ---------------------------------------------------------------- aniso conv
// wave per node, lane = channel. 8-deep batches (R12-proven best config).
__global__ void aniso_kernel(const bf16_t* __restrict__ diffb_,
                             const int* __restrict__ row_start,
                             const int4* __restrict__ csr_rec,
                             bf16_t* __restrict__ conv, int n) {
    const ushort* diffb = (const ushort*)diffb_;
    int wid = (blockIdx.x * 256 + threadIdx.x) >> 6;
    int lane = threadIdx.x & 63;
    if (wid >= n) return;
    int start = __builtin_amdgcn_readfirstlane(row_start[wid]);
    int end = __builtin_amdgcn_readfirstlane(row_start[wid + 1]);
    float a0 = 0.f, a1 = 0.f, a2 = 0.f, a3 = 0.f;
    int p = start;
    for (; p + 8 <= end; p += 8) {
        int s[8];
        uint wy[8], wz[8];
#pragma unroll
        for (int j = 0; j < 8; j++) {
            int4 rec = csr_rec[p + j];
            s[j] = rec.x; wy[j] = (uint)rec.y; wz[j] = (uint)rec.z;
        }
        float h[8];
#pragma unroll
        for (int j = 0; j < 8; j++)
            h[j] = bfu((uint)diffb[(size_t)s[j] * FEAT + lane]);
#pragma unroll
        for (int j = 0; j < 8; j++) {
            a0 += __uint_as_float(wy[j] << 16) * h[j];
            a1 += __uint_as_float(wy[j] & 0xffff0000u) * h[j];
            a2 += __uint_as_float(wz[j] << 16) * h[j];
            a3 += __uint_as_float(wz[j] & 0xffff0000u) * h[j];
        }
    }
    for (; p < end; p++) {
        int4 rec = csr_rec[p];
        float h0 = bfu((uint)diffb[(size_t)rec.x * FEAT + lane]);
        uint y = (uint)rec.y, z = (uint)rec.z;
        a0 += __uint_as_float(y << 16) * h0;
        a1 += __uint_as_float(y & 0xffff0000u) * h0;
        a2 += __uint_as_float(z << 16) * h0;
        a3 += __uint_as_float(z & 0xffff0000u) * h0;
    }
    size_t base = (size_t)wid * CONVF + lane;
    conv[base]       = (bf16_t)a0;
    conv[base + 64]  = (bf16_t)a1;
    conv[base + 128] = (bf16_t)a2;
    conv[base + 192] = (bf16_t)a3;
}

// ---------------------------------------------------------------- weights
__global__ void convw_kernel(const float* __restrict__ W, bf16_t* __restrict__ Wt,
                             int rows, int cols) {
    int idx = blockIdx.x * 256 + threadIdx.x;
    if (idx >= rows * cols) return;
    int o = idx / rows, f = idx % rows;
    Wt[idx] = (bf16_t)W[(size_t)f * cols + o];
}

// ---------------------------------------------------------------- GEMM
// Staging via global_load_lds width-16 into LINEAR LDS (LSTR=64).
#define BM 128
#define BN 128
#define BK 64
#define LSTR 64   // linear: required by global_load_lds (wave-uniform base + lane*16)

template <int EPI>
__global__ void gemm_bf16_kernel(const bf16_t* __restrict__ A,
                                 const bf16_t* __restrict__ Bt,
                                 const float* __restrict__ bias,
                                 void* __restrict__ Cout,
                                 int Nn, int K, int Mvalid) {
    __shared__ bf16_t Alds[BM * LSTR];
    __shared__ bf16_t Blds[BN * LSTR];
    const int t = threadIdx.x;
    const int lane = t & 63;
    const int wid = t >> 6;
    const int row0 = blockIdx.y * BM;
    const int col0 = blockIdx.x * BN;
    const int wr = (wid >> 1) * 64;
    const int wc = (wid & 1) * 64;

    f32x4 acc[4][4];
#pragma unroll
    for (int m = 0; m < 4; m++)
#pragma unroll
        for (int n = 0; n < 4; n++) acc[m][n] = (f32x4){0.f, 0.f, 0.f, 0.f};

    for (int kt = 0; kt < K; kt += BK) {
#pragma unroll
        for (int i = 0; i < 4; i++) {
            int idx = t + i * 256;        // 0..1023; lds byte off = idx*16
            int r = idx >> 3;             // 0..127
            int k8 = (idx & 7) * 8;
            int base8 = ((t & 192) + i * 256) * 8;   // wave-uniform elem base
            gload16(&A[(size_t)(row0 + r) * K + kt + k8], &Alds[base8]);
            gload16(&Bt[(size_t)(col0 + r) * K + kt + k8], &Blds[base8]);
        }
        __syncthreads();
#pragma unroll
        for (int kk = 0; kk < BK; kk += 32) {
            int ko = kk + ((lane >> 4) << 3);
            bf16x8 av[4], bv[4];
#pragma unroll
            for (int m = 0; m < 4; m++)
                av[m] = *(const bf16x8*)&Alds[(wr + m * 16 + (lane & 15)) * LSTR + ko];
#pragma unroll
            for (int n = 0; n < 4; n++)
                bv[n] = *(const bf16x8*)&Blds[(wc + n * 16 + (lane & 15)) * LSTR + ko];
#pragma unroll
            for (int m = 0; m < 4; m++)
#pragma unroll
                for (int n = 0; n < 4; n++)
                    acc[m][n] = __builtin_amdgcn_mfma_f32_16x16x32_bf16(
                        av[m], bv[n], acc[m][n], 0, 0, 0);
        }
        __syncthreads();
    }

#pragma unroll
    for (int n = 0; n < 4; n++) {
        int col = col0 + wc + n * 16 + (lane & 15);
        float bvl = bias[col];
#pragma unroll
        for (int m = 0; m < 4; m++) {
#pragma unroll
            for (int r = 0; r < 4; r++) {
                int row = row0 + wr + m * 16 + ((lane >> 4) << 2) + r;
                float v = acc[m][n][r] + bvl;
                if (EPI == 0) {
                    v = v > 0.f ? v : 0.f;
                    ((bf16_t*)Cout)[(size_t)row * Nn + col] = (bf16_t)v;
                } else {
                    if (row < Mvalid)
                        ((float*)Cout)[(size_t)row * Nn + col] = v;
                }
            }
        }
    }
}

// ---------------------------------------------------------------- normalize
__global__ void norm_kernel(float* __restrict__ out, int n) {
    int w = (blockIdx.x * 256 + threadIdx.x) >> 6;
    int lane = threadIdx.x & 63;
    if (w >= n) return;
    float4 v = *(float4*)&out[(size_t)w * OUT_F + lane * 4];
    float ss = v.x * v.x + v.y * v.y + v.z * v.z + v.w * v.w;
#pragma unroll
    for (int off = 32; off > 0; off >>= 1) ss += __shfl_xor(ss, off);
    float nrm = sqrtf(ss);
    nrm = nrm > 1e-12f ? nrm : 1e-12f;
    float sc = 1.f / nrm;
    v.x *= sc; v.y *= sc; v.z *= sc; v.w *= sc;
    *(float4*)&out[(size_t)w * OUT_F + lane * 4] = v;
}

// ---------------------------------------------------------------- launch
extern "C" void kernel_launch(void* const* d_in, const int* in_sizes, int n_in,
                              void* d_out, int out_size, void* d_ws, size_t ws_size,
                              hipStream_t stream) {
    const float* x      = (const float*)d_in[0];
    const float* evals  = (const float*)d_in[1];
    const float* evecs  = (const float*)d_in[2];
    const float* taus   = (const float*)d_in[3];
    const float* kvals  = (const float*)d_in[4];
    const int*   eidx   = (const int*)d_in[5];
    const float* W1     = (const float*)d_in[6];
    const float* b1     = (const float*)d_in[7];
    const float* W2     = (const float*)d_in[8];
    const float* b2     = (const float*)d_in[9];
    float* out = (float*)d_out;

    const int N = N_NODES, E = E_EDGES;
    const int* e_src = eidx;
    const int* e_dst = eidx + E;

    // workspace layout (bytes, 256-aligned)
    char* ws = (char*)d_ws;
    size_t off = 0;
    auto alloc = [&](size_t bytes) {
        void* p = ws + off;
        off = (off + bytes + 255) & ~(size_t)255;
        return p;
    };
    float* coeff       = (float*)alloc(2048 * 4);
    float* partial     = (float*)alloc((size_t)CPB * 2048 * 4);
    float* partial2    = (float*)alloc((size_t)RED1 * 2048 * 4);
    bf16_t* evb        = (bf16_t*)alloc((size_t)M_PAD * KEIG * 2);
    bf16_t* sc2t       = (bf16_t*)alloc((size_t)FEAT * KEIG * 2);
    bf16_t* diffb      = (bf16_t*)alloc((size_t)M_PAD * FEAT * 2);
    int*   gcursor     = (int*)alloc((size_t)NBC * 16 * 4);
    int*   coarse_base = (int*)alloc((size_t)(NBC + 1) * 4);
    int*   row_start   = (int*)alloc((size_t)(N + 1) * 4);
    // csr_rec (16B/edge, dead after aniso) aliases h1 (bf16 M_PAD x HID)
    size_t csr_bytes = (size_t)E * 16;
    size_t h1_bytes  = (size_t)M_PAD * HID * 2;
    int4*  csr_rec   = (int4*)alloc(csr_bytes > h1_bytes ? csr_bytes : h1_bytes);
    bf16_t* h1       = (bf16_t*)csr_rec;
    // bucket region (dead after radixB) aliases conv (written by aniso)
    size_t bucket_bytes = (size_t)NBC * CAPC * 16;
    size_t conv_bytes   = (size_t)M_PAD * CONVF * 2;
    int4*  bucket    = (int4*)alloc(bucket_bytes > conv_bytes ? bucket_bytes : conv_bytes);
    bf16_t* conv     = (bf16_t*)bucket;
    bf16_t* w1t      = (bf16_t*)alloc((size_t)HID * CONVF * 2);
    bf16_t* w2t      = (bf16_t*)alloc((size_t)OUT_F * HID * 2);
    (void)ws_size;

    hipMemsetAsync(gcursor, 0, (size_t)NBC * 16 * 4, stream);

    // diffusion: coeff (+evb conversion), 2-stage reduce, sc2t, MFMA GEMM
    coeff_partial_kernel<<<CPB, 256, 0, stream>>>(evecs, x, partial, evb, N);
    coeff_reduce1_kernel<<<RED1 * 8, 256, 0, stream>>>(partial, partial2);
    coeff_reduce2_kernel<<<8, 256, 0, stream>>>(partial2, coeff);
    sc2t_kernel<<<32, 256, 0, stream>>>(evals, taus, coeff, sc2t);
    diffusion_mfma_kernel<<<M_PAD / 128, 256, 0, stream>>>(evb, sc2t, diffb);

    // CSR build: staged radix (A: LDS-sorted coalesced bins; B: L2-local sort)
    radixA_kernel<<<PA_B, 256, 0, stream>>>(e_src, e_dst, kvals, gcursor, bucket, E);
    coarse_scan_kernel<<<1, 256, 0, stream>>>(gcursor, coarse_base, row_start);
    radixB_kernel<<<NBC, 256, 0, stream>>>(bucket, gcursor, coarse_base,
                                           csr_rec, row_start);

    // aniso conv -> bf16 [M_PAD x 256] (overwrites bucket region; CSR still live)
    aniso_kernel<<<(N + 3) / 4, 256, 0, stream>>>(diffb, row_start, csr_rec, conv, N);

    // weights -> transposed bf16
    convw_kernel<<<(CONVF * HID + 255) / 256, 256, 0, stream>>>(W1, w1t, CONVF, HID);
    convw_kernel<<<(HID * OUT_F + 255) / 256, 256, 0, stream>>>(W2, w2t, HID, OUT_F);

    // MLP (h1 overwrites csr_rec region — CSR dead after aniso)
    dim3 g1(HID / BN, M_PAD / BM);
    gemm_bf16_kernel<0><<<g1, 256, 0, stream>>>(conv, w1t, b1, h1, HID, CONVF, N);
    dim3 g2(OUT_F / BN, M_PAD / BM);
    gemm_bf16_kernel<1><<<g2, 256, 0, stream>>>(h1, w2t, b2, out, OUT_F, HID, N);

    // L2 normalize in place
    norm_kernel<<<(N + 3) / 4, 256, 0, stream>>>(out, N);
}

// Round 17
// 213.505 us; speedup vs baseline: 1.0799x; 1.0388x over previous
//
#include <hip/hip_runtime.h>

typedef __bf16 bf16_t;
typedef __attribute__((ext_vector_type(8))) __bf16 bf16x8;
typedef __attribute__((ext_vector_type(4))) float f32x4;
typedef unsigned int uint;
typedef unsigned short ushort;
typedef unsigned char uchar;

#define N_NODES 50000
#define C_IN 16
#define NT 4
#define K1 4
#define KEIG 128
#define E_EDGES 1600000
#define HID 512
#define OUT_F 256
#define FEAT 64           // NT*C
#define CONVF 256         // K1*FEAT
#define M_PAD 50048       // ceil(N/128)*128
#define CPB 1024          // coeff_partial blocks
#define RED1 64           // stage-1 output blocks (CPB/16)
// staged radix CSR build
#define SH_C 8            // coarse bucket = dst >> 8 (256 nodes per bucket)
#define NBC 196           // ceil(N/256)
#define CAPC 8704         // per-coarse-bucket record capacity (mean 8163 + 6 sigma)
#define PA_B 782          // pass A blocks (782*2048 >= E)

__device__ inline uint bfbits(float f) {
    bf16_t b = (bf16_t)f;
    return (uint)__builtin_bit_cast(unsigned short, b);
}
__device__ inline float bfu(uint u) {
    return __uint_as_float(u << 16);
}

// ---------------------------------------------------------------- coeff (+ evecs->bf16 fused)
__global__ void coeff_partial_kernel(const float* __restrict__ evecs,
                                     const float* __restrict__ x,
                                     float* __restrict__ partial,
                                     bf16_t* __restrict__ evb, int n) {
    __shared__ float lds[4 * 2048];
    int t = threadIdx.x, lane = t & 63, wid = t >> 6;
    int gw = blockIdx.x * 4 + wid;
    int total_w = gridDim.x * 4;
    int rpw = (n + total_w - 1) / total_w;
    int r0 = gw * rpw;
    int r1 = min(n, r0 + rpw);
    float acc0[16], acc1[16];
#pragma unroll
    for (int c = 0; c < 16; c++) { acc0[c] = 0.f; acc1[c] = 0.f; }
    for (int r = r0; r < r1; r++) {
        float e0 = evecs[(size_t)r * KEIG + lane];
        float e1 = evecs[(size_t)r * KEIG + 64 + lane];
        evb[(size_t)r * KEIG + lane] = (bf16_t)e0;
        evb[(size_t)r * KEIG + 64 + lane] = (bf16_t)e1;
        const float* xr = &x[(size_t)r * C_IN];
#pragma unroll
        for (int c = 0; c < 16; c++) {
            float xv = xr[c];
            acc0[c] += e0 * xv;
            acc1[c] += e1 * xv;
        }
    }
#pragma unroll
    for (int c = 0; c < 16; c++) {
        lds[wid * 2048 + c * 128 + lane] = acc0[c];
        lds[wid * 2048 + c * 128 + 64 + lane] = acc1[c];
    }
    __syncthreads();
    for (int idx = t; idx < 2048; idx += 256) {
        float s = lds[idx] + lds[2048 + idx] + lds[4096 + idx] + lds[6144 + idx];
        partial[(size_t)blockIdx.x * 2048 + idx] = s;
    }
}

__global__ void coeff_reduce1_kernel(const float* __restrict__ partial,
                                     float* __restrict__ partial2) {
    int g = blockIdx.x >> 3;
    int idx = (blockIdx.x & 7) * 256 + threadIdx.x;
    float s = 0.f;
#pragma unroll
    for (int j = 0; j < 16; j++)
        s += partial[(size_t)(g * 16 + j) * 2048 + idx];
    partial2[(size_t)g * 2048 + idx] = s;
}

// stage 2 + sc2t fused: finish coeff[c*128+k], emit 4 tau-scaled bf16 entries.
__global__ void coeff_reduce2_sc2t_kernel(const float* __restrict__ partial2,
                                          const float* __restrict__ evals,
                                          const float* __restrict__ taus,
                                          bf16_t* __restrict__ sc2t) {
    int idx = blockIdx.x * 256 + threadIdx.x;   // 0..2047 = c*128+k
    float s = 0.f;
#pragma unroll 8
    for (int b = 0; b < RED1; b++) s += partial2[(size_t)b * 2048 + idx];
    int c = idx >> 7, k = idx & 127;
    float ev = evals[k];
#pragma unroll
    for (int tt = 0; tt < NT; tt++) {
        float v = expf(-ev * taus[tt]) * s;
        sc2t[(tt * 16 + c) * KEIG + k] = (bf16_t)v;
    }
}

// diffb[M_PAD x 64] = evb[M_PAD x 128] @ sc2t[64 x 128]^T via MFMA
#define DSTR 136
__global__ void diffusion_mfma_kernel(const bf16_t* __restrict__ evb,
                                      const bf16_t* __restrict__ sc2t,
                                      bf16_t* __restrict__ diffb) {
    __shared__ bf16_t Alds[128 * DSTR];
    __shared__ bf16_t Blds[64 * DSTR];
    const int t = threadIdx.x;
    const int lane = t & 63;
    const int wid = t >> 6;
    const int row0 = blockIdx.x * 128;
#pragma unroll
    for (int i = 0; i < 8; i++) {
        int idx = t + i * 256;
        int r = idx >> 4;
        int k8 = (idx & 15) * 8;
        *(uint4*)&Alds[r * DSTR + k8] =
            *(const uint4*)&evb[(size_t)(row0 + r) * KEIG + k8];
    }
#pragma unroll
    for (int i = 0; i < 4; i++) {
        int idx = t + i * 256;
        int r = idx >> 4;
        int k8 = (idx & 15) * 8;
        *(uint4*)&Blds[r * DSTR + k8] =
            *(const uint4*)&sc2t[r * KEIG + k8];
    }
    __syncthreads();
    f32x4 acc[2][4];
#pragma unroll
    for (int m = 0; m < 2; m++)
#pragma unroll
        for (int n = 0; n < 4; n++) acc[m][n] = (f32x4){0.f, 0.f, 0.f, 0.f};
#pragma unroll
    for (int kk = 0; kk < 128; kk += 32) {
        int ko = kk + ((lane >> 4) << 3);
        bf16x8 av[2], bv[4];
#pragma unroll
        for (int m = 0; m < 2; m++)
            av[m] = *(const bf16x8*)&Alds[(wid * 32 + m * 16 + (lane & 15)) * DSTR + ko];
#pragma unroll
        for (int n = 0; n < 4; n++)
            bv[n] = *(const bf16x8*)&Blds[(n * 16 + (lane & 15)) * DSTR + ko];
#pragma unroll
        for (int m = 0; m < 2; m++)
#pragma unroll
            for (int n = 0; n < 4; n++)
                acc[m][n] = __builtin_amdgcn_mfma_f32_16x16x32_bf16(
                    av[m], bv[n], acc[m][n], 0, 0, 0);
    }
#pragma unroll
    for (int m = 0; m < 2; m++) {
#pragma unroll
        for (int n = 0; n < 4; n++) {
            int col = n * 16 + (lane & 15);
#pragma unroll
            for (int q = 0; q < 4; q++) {
                int row = row0 + wid * 32 + m * 16 + ((lane >> 4) << 2) + q;
                diffb[(size_t)row * FEAT + col] = (bf16_t)acc[m][n][q];
            }
        }
    }
}

// ---------------------------------------------------------------- CSR build: staged radix
// Record: [src | k0,k1 bf16 | k2,k3 bf16 | dst&255]
__global__ void radixA_kernel(const int* __restrict__ src,
                              const int* __restrict__ dst,
                              const float* __restrict__ kvals,
                              int* __restrict__ gcursor,     // NBC, stride 16 ints
                              int4* __restrict__ bucket, int E) {
    __shared__ int hist[256];
    __shared__ int lds_off[256];
    __shared__ int cnt2[256];
    __shared__ int run_base[256];
    __shared__ int4 recs[2048];
    __shared__ uchar posb[2048];
    int t = threadIdx.x;
    hist[t] = 0; cnt2[t] = 0;
    __syncthreads();
    int e0 = blockIdx.x * 2048;
    int total = min(2048, E - e0);
    int d[8];
#pragma unroll
    for (int j = 0; j < 8; j++) {
        int e = e0 + j * 256 + t;
        d[j] = (e < E) ? dst[e] : -1;
        if (d[j] >= 0) atomicAdd(&hist[d[j] >> SH_C], 1);
    }
    __syncthreads();
    int own = hist[t];
    lds_off[t] = own;
    __syncthreads();
    for (int o = 1; o < 256; o <<= 1) {
        int v = (t >= o) ? lds_off[t - o] : 0;
        __syncthreads();
        lds_off[t] += v;
        __syncthreads();
    }
    int excl = lds_off[t] - own;
    __syncthreads();
    lds_off[t] = excl;
    __syncthreads();
#pragma unroll
    for (int j = 0; j < 8; j++) {
        if (d[j] < 0) continue;
        int e = e0 + j * 256 + t;
        int b = d[j] >> SH_C;
        int r = atomicAdd(&cnt2[b], 1);
        int pos = lds_off[b] + r;
        uint w01 = bfbits(kvals[e]) | (bfbits(kvals[(size_t)E + e]) << 16);
        uint w23 = bfbits(kvals[2 * (size_t)E + e]) | (bfbits(kvals[3 * (size_t)E + e]) << 16);
        int4 rec;
        rec.x = src[e]; rec.y = (int)w01; rec.z = (int)w23; rec.w = d[j] & 255;
        recs[pos] = rec;
        posb[pos] = (uchar)b;
    }
    if (t < NBC) {
        int c = hist[t];
        run_base[t] = c ? atomicAdd(&gcursor[t * 16], c) : 0;
    }
    __syncthreads();
    for (int i = t; i < total; i += 256) {
        int b = posb[i];
        int g = run_base[b] + (i - lds_off[b]);
        if (g < CAPC) bucket[(size_t)b * CAPC + g] = recs[i];
    }
}

// Pass B: block per coarse bucket; output csr_rec is bucket-strided (base = b*CAPC),
// so no global prefix over buckets is needed. Writes row_start + row_end per node.
__global__ void radixB_kernel(const int4* __restrict__ bucket,
                              const int* __restrict__ gcursor,
                              int4* __restrict__ csr_rec,
                              int* __restrict__ row_start,
                              int* __restrict__ row_end) {
    __shared__ int hist[256];
    __shared__ int off[256];
    __shared__ int cnt2[256];
    int b = blockIdx.x, t = threadIdx.x;
    int n = min(gcursor[b * 16], CAPC);
    int base = b * CAPC;
    hist[t] = 0; cnt2[t] = 0;
    __syncthreads();
    const int4* brec = &bucket[(size_t)b * CAPC];
    for (int i = t; i < n; i += 256) atomicAdd(&hist[brec[i].w & 255], 1);
    __syncthreads();
    int own = hist[t];
    off[t] = own;
    __syncthreads();
    for (int o = 1; o < 256; o <<= 1) {
        int v = (t >= o) ? off[t - o] : 0;
        __syncthreads();
        off[t] += v;
        __syncthreads();
    }
    int excl = off[t] - own;
    __syncthreads();
    off[t] = excl;
    __syncthreads();
    int g = b * 256 + t;
    if (g < N_NODES) {
        row_start[g] = base + off[t];
        row_end[g] = base + off[t] + own;
    }
    for (int i = t; i < n; i += 256) {
        int4 rec = brec[i];
        int w = rec.w & 255;
        int r = atomicAdd(&cnt2[w], 1);
        csr_rec[(size_t)(base + off[w] + r)] = rec;
    }
}

// ---------------------------------------------------------------- aniso conv
// wave per node, lane = channel. 8-deep batches (R12-proven best config).
__global__ void aniso_kernel(const bf16_t* __restrict__ diffb_,
                             const int* __restrict__ row_start,
                             const int* __restrict__ row_end,
                             const int4* __restrict__ csr_rec,
                             bf16_t* __restrict__ conv, int n) {
    const ushort* diffb = (const ushort*)diffb_;
    int wid = (blockIdx.x * 256 + threadIdx.x) >> 6;
    int lane = threadIdx.x & 63;
    if (wid >= n) return;
    int start = __builtin_amdgcn_readfirstlane(row_start[wid]);
    int end = __builtin_amdgcn_readfirstlane(row_end[wid]);
    float a0 = 0.f, a1 = 0.f, a2 = 0.f, a3 = 0.f;
    int p = start;
    for (; p + 8 <= end; p += 8) {
        int s[8];
        uint wy[8], wz[8];
#pragma unroll
        for (int j = 0; j < 8; j++) {
            int4 rec = csr_rec[p + j];
            s[j] = rec.x; wy[j] = (uint)rec.y; wz[j] = (uint)rec.z;
        }
        float h[8];
#pragma unroll
        for (int j = 0; j < 8; j++)
            h[j] = bfu((uint)diffb[(size_t)s[j] * FEAT + lane]);
#pragma unroll
        for (int j = 0; j < 8; j++) {
            a0 += __uint_as_float(wy[j] << 16) * h[j];
            a1 += __uint_as_float(wy[j] & 0xffff0000u) * h[j];
            a2 += __uint_as_float(wz[j] << 16) * h[j];
            a3 += __uint_as_float(wz[j] & 0xffff0000u) * h[j];
        }
    }
    for (; p < end; p++) {
        int4 rec = csr_rec[p];
        float h0 = bfu((uint)diffb[(size_t)rec.x * FEAT + lane]);
        uint y = (uint)rec.y, z = (uint)rec.z;
        a0 += __uint_as_float(y << 16) * h0;
        a1 += __uint_as_float(y & 0xffff0000u) * h0;
        a2 += __uint_as_float(z << 16) * h0;
        a3 += __uint_as_float(z & 0xffff0000u) * h0;
    }
    size_t base = (size_t)wid * CONVF + lane;
    conv[base]       = (bf16_t)a0;
    conv[base + 64]  = (bf16_t)a1;
    conv[base + 128] = (bf16_t)a2;
    conv[base + 192] = (bf16_t)a3;
}

// ---------------------------------------------------------------- weights (both, one launch)
// w1t[o][f] = W1[f][o] (o<HID, f<CONVF); w2t[o][f] = W2[f][o] (o<OUT_F, f<HID)
__global__ void convw_all_kernel(const float* __restrict__ W1,
                                 const float* __restrict__ W2,
                                 bf16_t* __restrict__ w1t,
                                 bf16_t* __restrict__ w2t) {
    int idx = blockIdx.x * 256 + threadIdx.x;
    const int n1 = CONVF * HID;
    if (idx < n1) {
        int o = idx / CONVF, f = idx % CONVF;
        w1t[idx] = (bf16_t)W1[(size_t)f * HID + o];
    } else {
        int j = idx - n1;               // < HID*OUT_F
        int o = j / HID, f = j % HID;
        w2t[j] = (bf16_t)W2[(size_t)f * OUT_F + o];
    }
}

// ---------------------------------------------------------------- GEMM (reg-staged, R12-proven)
#define BM 128
#define BN 128
#define BK 64
#define LSTR 72   // LDS row stride in elements (144 B: 16B-aligned, breaks bank-conflict stride)

template <int EPI>
__global__ void gemm_bf16_kernel(const bf16_t* __restrict__ A,
                                 const bf16_t* __restrict__ Bt,
                                 const float* __restrict__ bias,
                                 void* __restrict__ Cout,
                                 int Nn, int K, int Mvalid) {
    __shared__ bf16_t Alds[BM * LSTR];
    __shared__ bf16_t Blds[BN * LSTR];
    const int t = threadIdx.x;
    const int lane = t & 63;
    const int wid = t >> 6;
    const int row0 = blockIdx.y * BM;
    const int col0 = blockIdx.x * BN;
    const int wr = (wid >> 1) * 64;
    const int wc = (wid & 1) * 64;

    f32x4 acc[4][4];
#pragma unroll
    for (int m = 0; m < 4; m++)
#pragma unroll
        for (int n = 0; n < 4; n++) acc[m][n] = (f32x4){0.f, 0.f, 0.f, 0.f};

    for (int kt = 0; kt < K; kt += BK) {
#pragma unroll
        for (int i = 0; i < 4; i++) {
            int idx = t + i * 256;
            int r = idx >> 3;
            int k8 = (idx & 7) * 8;
            *(uint4*)&Alds[r * LSTR + k8] =
                *(const uint4*)&A[(size_t)(row0 + r) * K + kt + k8];
            *(uint4*)&Blds[r * LSTR + k8] =
                *(const uint4*)&Bt[(size_t)(col0 + r) * K + kt + k8];
        }
        __syncthreads();
#pragma unroll
        for (int kk = 0; kk < BK; kk += 32) {
            int ko = kk + ((lane >> 4) << 3);
            bf16x8 av[4], bv[4];
#pragma unroll
            for (int m = 0; m < 4; m++)
                av[m] = *(const bf16x8*)&Alds[(wr + m * 16 + (lane & 15)) * LSTR + ko];
#pragma unroll
            for (int n = 0; n < 4; n++)
                bv[n] = *(const bf16x8*)&Blds[(wc + n * 16 + (lane & 15)) * LSTR + ko];
#pragma unroll
            for (int m = 0; m < 4; m++)
#pragma unroll
                for (int n = 0; n < 4; n++)
                    acc[m][n] = __builtin_amdgcn_mfma_f32_16x16x32_bf16(
                        av[m], bv[n], acc[m][n], 0, 0, 0);
        }
        __syncthreads();
    }

#pragma unroll
    for (int n = 0; n < 4; n++) {
        int col = col0 + wc + n * 16 + (lane & 15);
        float bvl = bias[col];
#pragma unroll
        for (int m = 0; m < 4; m++) {
#pragma unroll
            for (int r = 0; r < 4; r++) {
                int row = row0 + wr + m * 16 + ((lane >> 4) << 2) + r;
                float v = acc[m][n][r] + bvl;
                if (EPI == 0) {
                    v = v > 0.f ? v : 0.f;
                    ((bf16_t*)Cout)[(size_t)row * Nn + col] = (bf16_t)v;
                } else {
                    if (row < Mvalid)
                        ((float*)Cout)[(size_t)row * Nn + col] = v;
                }
            }
        }
    }
}

// ---------------------------------------------------------------- normalize
__global__ void norm_kernel(float* __restrict__ out, int n) {
    int w = (blockIdx.x * 256 + threadIdx.x) >> 6;
    int lane = threadIdx.x & 63;
    if (w >= n) return;
    float4 v = *(float4*)&out[(size_t)w * OUT_F + lane * 4];
    float ss = v.x * v.x + v.y * v.y + v.z * v.z + v.w * v.w;
#pragma unroll
    for (int off = 32; off > 0; off >>= 1) ss += __shfl_xor(ss, off);
    float nrm = sqrtf(ss);
    nrm = nrm > 1e-12f ? nrm : 1e-12f;
    float sc = 1.f / nrm;
    v.x *= sc; v.y *= sc; v.z *= sc; v.w *= sc;
    *(float4*)&out[(size_t)w * OUT_F + lane * 4] = v;
}

// ---------------------------------------------------------------- launch
extern "C" void kernel_launch(void* const* d_in, const int* in_sizes, int n_in,
                              void* d_out, int out_size, void* d_ws, size_t ws_size,
                              hipStream_t stream) {
    const float* x      = (const float*)d_in[0];
    const float* evals  = (const float*)d_in[1];
    const float* evecs  = (const float*)d_in[2];
    const float* taus   = (const float*)d_in[3];
    const float* kvals  = (const float*)d_in[4];
    const int*   eidx   = (const int*)d_in[5];
    const float* W1     = (const float*)d_in[6];
    const float* b1     = (const float*)d_in[7];
    const float* W2     = (const float*)d_in[8];
    const float* b2     = (const float*)d_in[9];
    float* out = (float*)d_out;

    const int N = N_NODES, E = E_EDGES;
    const int* e_src = eidx;
    const int* e_dst = eidx + E;

    // workspace layout (bytes, 256-aligned)
    char* ws = (char*)d_ws;
    size_t off = 0;
    auto alloc = [&](size_t bytes) {
        void* p = ws + off;
        off = (off + bytes + 255) & ~(size_t)255;
        return p;
    };
    float* partial     = (float*)alloc((size_t)CPB * 2048 * 4);
    float* partial2    = (float*)alloc((size_t)RED1 * 2048 * 4);
    bf16_t* evb        = (bf16_t*)alloc((size_t)M_PAD * KEIG * 2);
    bf16_t* sc2t       = (bf16_t*)alloc((size_t)FEAT * KEIG * 2);
    bf16_t* diffb      = (bf16_t*)alloc((size_t)M_PAD * FEAT * 2);
    int*   gcursor     = (int*)alloc((size_t)NBC * 16 * 4);
    int*   row_start   = (int*)alloc((size_t)N * 4);
    int*   row_end     = (int*)alloc((size_t)N * 4);
    // csr_rec (bucket-strided: NBC*CAPC recs, dead after aniso) aliases h1
    size_t csr_bytes = (size_t)NBC * CAPC * 16;
    size_t h1_bytes  = (size_t)M_PAD * HID * 2;
    int4*  csr_rec   = (int4*)alloc(csr_bytes > h1_bytes ? csr_bytes : h1_bytes);
    bf16_t* h1       = (bf16_t*)csr_rec;
    // bucket region (dead after radixB) aliases conv (written by aniso)
    size_t bucket_bytes = (size_t)NBC * CAPC * 16;
    size_t conv_bytes   = (size_t)M_PAD * CONVF * 2;
    int4*  bucket    = (int4*)alloc(bucket_bytes > conv_bytes ? bucket_bytes : conv_bytes);
    bf16_t* conv     = (bf16_t*)bucket;
    bf16_t* w1t      = (bf16_t*)alloc((size_t)HID * CONVF * 2);
    bf16_t* w2t      = (bf16_t*)alloc((size_t)OUT_F * HID * 2);
    (void)ws_size;

    hipMemsetAsync(gcursor, 0, (size_t)NBC * 16 * 4, stream);

    // diffusion: coeff (+evb conversion), reduce1, reduce2+sc2t fused, MFMA GEMM
    coeff_partial_kernel<<<CPB, 256, 0, stream>>>(evecs, x, partial, evb, N);
    coeff_reduce1_kernel<<<RED1 * 8, 256, 0, stream>>>(partial, partial2);
    coeff_reduce2_sc2t_kernel<<<8, 256, 0, stream>>>(partial2, evals, taus, sc2t);
    diffusion_mfma_kernel<<<M_PAD / 128, 256, 0, stream>>>(evb, sc2t, diffb);

    // CSR build: staged radix (A: LDS-sorted coalesced bins; B: bucket-strided sort)
    radixA_kernel<<<PA_B, 256, 0, stream>>>(e_src, e_dst, kvals, gcursor, bucket, E);
    radixB_kernel<<<NBC, 256, 0, stream>>>(bucket, gcursor, csr_rec, row_start, row_end);

    // aniso conv -> bf16 [M_PAD x 256] (overwrites bucket region; CSR still live)
    aniso_kernel<<<(N + 3) / 4, 256, 0, stream>>>(diffb, row_start, row_end,
                                                  csr_rec, conv, N);

    // weights -> transposed bf16 (single launch)
    convw_all_kernel<<<(CONVF * HID + HID * OUT_F) / 256, 256, 0, stream>>>(W1, W2,
                                                                            w1t, w2t);

    // MLP (h1 overwrites csr_rec region — CSR dead after aniso)
    dim3 g1(HID / BN, M_PAD / BM);
    gemm_bf16_kernel<0><<<g1, 256, 0, stream>>>(conv, w1t, b1, h1, HID, CONVF, N);
    dim3 g2(OUT_F / BN, M_PAD / BM);
    gemm_bf16_kernel<1><<<g2, 256, 0, stream>>>(h1, w2t, b2, out, OUT_F, HID, N);

    // L2 normalize in place
    norm_kernel<<<(N + 3) / 4, 256, 0, stream>>>(out, N);
}